// Round 7
// baseline (3037.526 us; speedup 1.0000x reference)
//
#include <hip/hip_runtime.h>
#include <hip/hip_bf16.h>

typedef float f32x4 __attribute__((ext_vector_type(4)));
typedef short s16x8 __attribute__((ext_vector_type(8)));
typedef int   i32x4 __attribute__((ext_vector_type(4)));
typedef _Float16 h16x8 __attribute__((ext_vector_type(8)));

#define NV 1024
#define ND 1024
#define NJ 1024
#define NB 64
#define NU 512
#define NT 513            // U+1 steps
#define G3 3072           // 3*D
#define SLOT 65536        // NB*ND elements per h slot
#define NWG 64            // recurrence workgroups
#define CANARY 0x7FFF7FFFu   // fp16 all-ones NaN pair: unreachable by f2h(h)

static __device__ __forceinline__ unsigned short f2h(float f) {
  union { _Float16 h; unsigned short u; } x; x.h = (_Float16)f;   // RNE
  return x.u;
}

// Swizzled fp16 layout (K=1024 -> 32 k-chunks of 32):
// element (r,k) -> flat ((r>>4)*32 + (k>>5))*512 + ((r&15) | (((k>>3)&3)<<4))*8 + (k&7)
// = exact mfma_f32_16x16x32_f16 A/B fragment order (64 lanes x 16B contiguous).
static __device__ __forceinline__ void unswizzle(long e, int& r, int& k) {
  long blk = e >> 9; int l = (int)((e >> 3) & 63); int j = (int)(e & 7);
  r = (int)(blk >> 5) * 16 + (l & 15);
  k = ((int)(blk & 31)) * 32 + ((l >> 4) << 3) + j;
}

__global__ void predictor_prep(const float* __restrict__ whh, const float* __restrict__ wih,
                               const float* __restrict__ em, const float* __restrict__ lw,
                               const float* __restrict__ bih, const float* __restrict__ bhh,
                               const float* __restrict__ init,
                               unsigned short* __restrict__ wh_sw, unsigned short* __restrict__ wi_sw,
                               unsigned short* __restrict__ em_sw, unsigned short* __restrict__ lw_sw,
                               float* __restrict__ bias_sum, unsigned short* __restrict__ hs) {
  long e = (long)blockIdx.x * 256 + threadIdx.x;
  const long nbig = 3145728, nsm = 1048576;
  if (e < nbig) { int r, k; unswizzle(e, r, k); wh_sw[e] = f2h(whh[(long)r * 1024 + k]); return; }
  e -= nbig;
  if (e < nbig) { int r, k; unswizzle(e, r, k); wi_sw[e] = f2h(wih[(long)r * 1024 + k]); return; }
  e -= nbig;
  if (e < nsm) { int r, k; unswizzle(e, r, k); em_sw[e] = f2h(em[(long)r * 1024 + k]); return; }
  e -= nsm;
  if (e < nsm) { int r, k; unswizzle(e, r, k); lw_sw[e] = f2h(lw[(long)r * 1024 + k]); return; }
  e -= nsm;
  if (e < 65536) { int r, k; unswizzle(e, r, k); hs[e] = f2h(init[k]); return; }
  e -= 65536;
  if (e < 3072) { bias_sum[e] = bih[e] + bhh[e]; return; }
  e -= 3072;
  if (e < 4202496) {  // canary-fill slots 1..513 (513*65536 ushort / 8 per thread)
    s16x8 c = { (short)0x7FFF, (short)0x7FFF, (short)0x7FFF, (short)0x7FFF,
                (short)0x7FFF, (short)0x7FFF, (short)0x7FFF, (short)0x7FFF };
    *(s16x8*)(hs + 65536 + e * 8) = c;
  }
}

// Generic fp16 GEMM: out[row, nt*64 .. +64) = A_chunk @ B^T + bias (fragment layouts).
__global__ __launch_bounds__(256) void predictor_gemm(
    const unsigned short* __restrict__ A, long a_chunk_stride,
    const unsigned short* __restrict__ Bw,
    const float* __restrict__ bias, float* __restrict__ out,
    int rowmul_i, int rowmul_c, int out_stride) {
  const int nt = blockIdx.x, chunk = blockIdx.y;
  const int tid = threadIdx.x, lane = tid & 63, wave = tid >> 6;
  const unsigned short* Ab = A + (long)chunk * a_chunk_stride + wave * 16384 + lane * 8;
  const unsigned short* Bb = Bw + (long)nt * 65536 + lane * 8;
  f32x4 a0 = {0,0,0,0}, a1 = {0,0,0,0}, a2 = {0,0,0,0}, a3 = {0,0,0,0};
#pragma unroll 4
  for (int kc = 0; kc < 32; ++kc) {
    h16x8 av = __builtin_bit_cast(h16x8, *(const s16x8*)(Ab + kc * 512));
    h16x8 w0 = __builtin_bit_cast(h16x8, *(const s16x8*)(Bb + kc * 512));
    h16x8 w1 = __builtin_bit_cast(h16x8, *(const s16x8*)(Bb + 16384 + kc * 512));
    h16x8 w2 = __builtin_bit_cast(h16x8, *(const s16x8*)(Bb + 32768 + kc * 512));
    h16x8 w3 = __builtin_bit_cast(h16x8, *(const s16x8*)(Bb + 49152 + kc * 512));
    a0 = __builtin_amdgcn_mfma_f32_16x16x32_f16(av, w0, a0, 0, 0, 0);
    a1 = __builtin_amdgcn_mfma_f32_16x16x32_f16(av, w1, a1, 0, 0, 0);
    a2 = __builtin_amdgcn_mfma_f32_16x16x32_f16(av, w2, a2, 0, 0, 0);
    a3 = __builtin_amdgcn_mfma_f32_16x16x32_f16(av, w3, a3, 0, 0, 0);
  }
  const int q = lane >> 4, nl = lane & 15, colbase = nt << 6;
#pragma unroll
  for (int j = 0; j < 4; ++j) {
    int il = (wave << 4) + (q << 2) + j;
    long row = (long)il * rowmul_i + (long)chunk * rowmul_c;
    float* orow = out + row * out_stride + colbase;
    orow[nl]      = a0[j] + bias[colbase + nl];
    orow[16 + nl] = a1[j] + bias[colbase + 16 + nl];
    orow[32 + nl] = a2[j] + bias[colbase + 32 + nl];
    orow[48 + nl] = a3[j] + bias[colbase + 48 + nl];
  }
}

#define PINSTAGE(CNT, B)                                                        \
  asm volatile("s_waitcnt vmcnt(" #CNT ")"                                      \
    : "+v"(hf[(B)*8+0]), "+v"(hf[(B)*8+1]), "+v"(hf[(B)*8+2]), "+v"(hf[(B)*8+3]), \
      "+v"(hf[(B)*8+4]), "+v"(hf[(B)*8+5]), "+v"(hf[(B)*8+6]), "+v"(hf[(B)*8+7]) :: "memory")

// Persistent recurrence v9 (= R6 structure + SENTINEL DATA-POLL, no flags):
//  - producer: LDS transpose (wave-private) -> 512-B coalesced sc1 store,
//    FIRE AND FORGET. No drain, no flag. The store is retired for free by the
//    producer's own next-iteration poll vmcnt(0).
//  - consumer wave w: lane l watches producer l's 512-B block: ONE canary
//    sentinel dword per 64-B write-coalescing sector (8 loads/lane/round).
//    A sector commits atomically (dwordx2 x 8 lanes = one 64-B VMEM write),
//    so sentinel != CANARY  =>  whole sector visible. All 8 pass on all 64
//    lanes => full 32-KB h block visible; then issue the 32 big loads once.
//    Rounds are RT-paced (vmcnt(0) on the 8 loads), no s_sleep quantization.
//    This fixes R2: retries are 8 cheap dwords, not 128 B/lane, and the
//    heavy load is issued exactly once, after confirmation.
//  - everything else identical to R6 (weights in LDS, no steady-state
//    barriers, 4 independent batch-group chains, staged vmcnt consume).
__global__ __launch_bounds__(256, 1) void predictor_rnn(
    const unsigned short* __restrict__ wh_sw, const float* __restrict__ gtab,
    const int* __restrict__ y, const float* __restrict__ init,
    unsigned short* __restrict__ hs) {
  __shared__ unsigned short wlds[49152];  // 3 gates x 32 kc x 512 elems, 96 KB
  __shared__ unsigned short tbuf[1024];   // h store transpose, 2 KB (wave-private quarters)
  const int wg = blockIdx.x, tid = threadIdx.x, lane = tid & 63, w = tid >> 6;
  const int q = lane >> 4, dloc = lane & 15, dg = (wg << 4) + dloc;

  // ---- stage this WG's weight slice into LDS (3 contiguous 32-KB blocks) ----
  for (int g = 0; g < 3; ++g) {
    const unsigned short* src = wh_sw + ((long)(g * 64 + wg) << 14);
#pragma unroll
    for (int i = 0; i < 8; ++i) {
      int c = i * 256 + tid;                  // 2048 chunks of 8 elems per gate
      *(s16x8*)&wlds[g * 16384 + c * 8] = *(const s16x8*)&src[c * 8];
    }
  }
  __syncthreads();   // weights visible to all waves; only barrier in the kernel

  float hreg[4];
#pragma unroll
  for (int j = 0; j < 4; ++j) hreg[j] = init[dg];

  const s16x8* wbase = (const s16x8*)wlds + lane;   // + kc*64 (+2048/gate) below

  for (int t = 1; t <= NT; ++t) {
    // ---- issue gate-table prefetch (12 loads; drained for free by the poll) ----
    float gr[4], gz[4], gn[4];
#pragma unroll
    for (int j = 0; j < 4; ++j) {
      int b = (w << 4) + (q << 2) + j;
      int tok = (t == 1) ? 0 : y[b * NU + (t - 2)];
      const float* g = gtab + (long)tok * G3 + dg;
      asm volatile("global_load_dword %0, %1, off" : "=v"(gr[j]) : "v"(g) : "memory");
      asm volatile("global_load_dword %0, %1, off" : "=v"(gz[j]) : "v"(g + 1024) : "memory");
      asm volatile("global_load_dword %0, %1, off" : "=v"(gn[j]) : "v"(g + 2048) : "memory");
    }

    // own batch group's full h row-block: contiguous 32 KB (64 producers x 512 B)
    const unsigned short* hprev = hs + (long)(t - 1) * SLOT + (w << 14);
    unsigned short* hcur = hs + (long)t * SLOT;

    // ---- sentinel data-poll: lane l checks 8 sector-sentinels of producer l ----
    if (t > 1) {
      const unsigned int* sp = (const unsigned int*)hprev + (lane << 7);  // l*512B
      for (;;) {
        unsigned int s0, s1, s2, s3, s4, s5, s6, s7;
        asm volatile("global_load_dword %0, %1, off sc1" : "=v"(s0) : "v"(sp +   0) : "memory");
        asm volatile("global_load_dword %0, %1, off sc1" : "=v"(s1) : "v"(sp +  16) : "memory");
        asm volatile("global_load_dword %0, %1, off sc1" : "=v"(s2) : "v"(sp +  32) : "memory");
        asm volatile("global_load_dword %0, %1, off sc1" : "=v"(s3) : "v"(sp +  48) : "memory");
        asm volatile("global_load_dword %0, %1, off sc1" : "=v"(s4) : "v"(sp +  64) : "memory");
        asm volatile("global_load_dword %0, %1, off sc1" : "=v"(s5) : "v"(sp +  80) : "memory");
        asm volatile("global_load_dword %0, %1, off sc1" : "=v"(s6) : "v"(sp +  96) : "memory");
        asm volatile("global_load_dword %0, %1, off sc1" : "=v"(s7) : "v"(sp + 112) : "memory");
        asm volatile("s_waitcnt vmcnt(0)"
          : "+v"(s0), "+v"(s1), "+v"(s2), "+v"(s3),
            "+v"(s4), "+v"(s5), "+v"(s6), "+v"(s7) :: "memory");
        int ok = (s0 != CANARY) & (s1 != CANARY) & (s2 != CANARY) & (s3 != CANARY) &
                 (s4 != CANARY) & (s5 != CANARY) & (s6 != CANARY) & (s7 != CANARY);
        if (__all(ok)) break;
      }
    }
    // tie gtab registers (vmcnt already 0 after the poll)
    asm volatile("s_waitcnt vmcnt(0)"
      : "+v"(gr[0]), "+v"(gr[1]), "+v"(gr[2]), "+v"(gr[3]),
        "+v"(gz[0]), "+v"(gz[1]), "+v"(gz[2]), "+v"(gz[3]),
        "+v"(gn[0]), "+v"(gn[1]), "+v"(gn[2]), "+v"(gn[3]) :: "memory");

    // ---- issue all 32 h-fragment loads, consume in 4 staged groups ----
    i32x4 hf[32];
#pragma unroll
    for (int i = 0; i < 32; ++i) {
      const unsigned short* a = hprev + i * 512 + lane * 8;
      asm volatile("global_load_dwordx4 %0, %1, off sc1" : "=v"(hf[i]) : "v"(a) : "memory");
    }
    f32x4 aR = {0,0,0,0}, aZ = {0,0,0,0}, aN = {0,0,0,0};
    {
      PINSTAGE(24, 0);
#pragma unroll
      for (int i = 0; i < 8; ++i) { int kc = i; h16x8 a = __builtin_bit_cast(h16x8, hf[kc]);
        h16x8 wr = __builtin_bit_cast(h16x8, wbase[kc * 64]);
        h16x8 wz = __builtin_bit_cast(h16x8, wbase[2048 + kc * 64]);
        h16x8 wn = __builtin_bit_cast(h16x8, wbase[4096 + kc * 64]);
        aR = __builtin_amdgcn_mfma_f32_16x16x32_f16(a, wr, aR, 0, 0, 0);
        aZ = __builtin_amdgcn_mfma_f32_16x16x32_f16(a, wz, aZ, 0, 0, 0);
        aN = __builtin_amdgcn_mfma_f32_16x16x32_f16(a, wn, aN, 0, 0, 0); }
      PINSTAGE(16, 1);
#pragma unroll
      for (int i = 0; i < 8; ++i) { int kc = 8 + i; h16x8 a = __builtin_bit_cast(h16x8, hf[kc]);
        h16x8 wr = __builtin_bit_cast(h16x8, wbase[kc * 64]);
        h16x8 wz = __builtin_bit_cast(h16x8, wbase[2048 + kc * 64]);
        h16x8 wn = __builtin_bit_cast(h16x8, wbase[4096 + kc * 64]);
        aR = __builtin_amdgcn_mfma_f32_16x16x32_f16(a, wr, aR, 0, 0, 0);
        aZ = __builtin_amdgcn_mfma_f32_16x16x32_f16(a, wz, aZ, 0, 0, 0);
        aN = __builtin_amdgcn_mfma_f32_16x16x32_f16(a, wn, aN, 0, 0, 0); }
      PINSTAGE(8, 2);
#pragma unroll
      for (int i = 0; i < 8; ++i) { int kc = 16 + i; h16x8 a = __builtin_bit_cast(h16x8, hf[kc]);
        h16x8 wr = __builtin_bit_cast(h16x8, wbase[kc * 64]);
        h16x8 wz = __builtin_bit_cast(h16x8, wbase[2048 + kc * 64]);
        h16x8 wn = __builtin_bit_cast(h16x8, wbase[4096 + kc * 64]);
        aR = __builtin_amdgcn_mfma_f32_16x16x32_f16(a, wr, aR, 0, 0, 0);
        aZ = __builtin_amdgcn_mfma_f32_16x16x32_f16(a, wz, aZ, 0, 0, 0);
        aN = __builtin_amdgcn_mfma_f32_16x16x32_f16(a, wn, aN, 0, 0, 0); }
      PINSTAGE(0, 3);
#pragma unroll
      for (int i = 0; i < 8; ++i) { int kc = 24 + i; h16x8 a = __builtin_bit_cast(h16x8, hf[kc]);
        h16x8 wr = __builtin_bit_cast(h16x8, wbase[kc * 64]);
        h16x8 wz = __builtin_bit_cast(h16x8, wbase[2048 + kc * 64]);
        h16x8 wn = __builtin_bit_cast(h16x8, wbase[4096 + kc * 64]);
        aR = __builtin_amdgcn_mfma_f32_16x16x32_f16(a, wr, aR, 0, 0, 0);
        aZ = __builtin_amdgcn_mfma_f32_16x16x32_f16(a, wz, aZ, 0, 0, 0);
        aN = __builtin_amdgcn_mfma_f32_16x16x32_f16(a, wn, aN, 0, 0, 0); }
    }

    // ---- gate epilogue (full sums already in acc); fp16 h to wave-private tbuf ----
#pragma unroll
    for (int j = 0; j < 4; ++j) {
      float r = 1.f / (1.f + __expf(-(gr[j] + aR[j])));
      float z = 1.f / (1.f + __expf(-(gz[j] + aZ[j])));
      float np = gn[j] + r * aN[j];
      float e2 = __expf(-2.f * fabsf(np));              // overflow-safe tanh
      float tn = (1.f - e2) / (1.f + e2);
      tn = np < 0.f ? -tn : tn;
      float hnew = (1.f - z) * tn + z * hreg[j];
      hreg[j] = hnew;
      tbuf[(w << 8) + ((((q << 2) + j) | ((dloc >> 3) << 4)) << 3) + (dloc & 7)] = f2h(hnew);
    }
    // wave-private transpose: wave-local LDS ordering is enough (no barrier)
    asm volatile("s_waitcnt lgkmcnt(0)" ::: "memory");

    // ---- publish: 512-B coalesced sc1 store, FIRE AND FORGET ----
    {
      unsigned long long pv = *(const unsigned long long*)(tbuf + (w << 8) + lane * 4);
      unsigned short* gp = hcur + ((long)(w * 32 + (wg >> 1)) << 9) + ((wg & 1) << 8) + lane * 4;
      asm volatile("global_store_dwordx2 %0, %1, off sc1" :: "v"(gp), "v"(pv) : "memory");
      // no drain, no flag: consumers sentinel-poll the data; our next
      // iteration's poll vmcnt(0) retires this store for free.
    }
  }
}

extern "C" void kernel_launch(void* const* d_in, const int* in_sizes, int n_in,
                              void* d_out, int out_size, void* d_ws, size_t ws_size,
                              hipStream_t stream) {
  const int*   y    = (const int*)d_in[0];
  const float* em   = (const float*)d_in[1];
  const float* wih  = (const float*)d_in[2];
  const float* bih  = (const float*)d_in[3];
  const float* whh  = (const float*)d_in[4];
  const float* bhh  = (const float*)d_in[5];
  const float* lw   = (const float*)d_in[6];
  const float* lb   = (const float*)d_in[7];
  const float* init = (const float*)d_in[8];
  float* out = (float*)d_out;

  char* ws = (char*)d_ws;
  size_t off = 0;
  auto alloc = [&](size_t n) { void* p = ws + off; off += (n + 255) & ~(size_t)255; return p; };
  unsigned short* wh_sw   = (unsigned short*)alloc(6291456);    // W_hh fp16 swizzled
  unsigned short* wi_sw   = (unsigned short*)alloc(6291456);    // W_ih fp16 swizzled
  unsigned short* em_sw   = (unsigned short*)alloc(2097152);    // embed fp16 swizzled
  unsigned short* lw_sw   = (unsigned short*)alloc(2097152);    // linear_w fp16 swizzled
  float*          gtab    = (float*)alloc(12582912);            // [V,3072] token gate table
  float*          bias_sum= (float*)alloc(12288);               // bias_ih + bias_hh
  unsigned short* hs      = (unsigned short*)alloc(67371008UL); // 514 h slots, fp16 swizzled
  (void)ws_size; (void)in_sizes; (void)n_in; (void)out_size;

  predictor_prep<<<dim3(49452), dim3(256), 0, stream>>>(
      whh, wih, em, lw, bih, bhh, init, wh_sw, wi_sw, em_sw, lw_sw, bias_sum, hs);
  predictor_gemm<<<dim3(48, 16), dim3(256), 0, stream>>>(
      em_sw, 65536L, wi_sw, bias_sum, gtab, /*rowmul_i=*/1, /*rowmul_c=*/64, /*stride=*/3072);
  predictor_rnn<<<dim3(NWG), dim3(256), 0, stream>>>(wh_sw, gtab, y, init, hs);
  predictor_gemm<<<dim3(16, 513), dim3(256), 0, stream>>>(
      hs + 65536, 65536L, lw_sw, lb, out, /*rowmul_i=*/513, /*rowmul_c=*/1, /*stride=*/1024);
}